// Round 1
// baseline (274.425 us; speedup 1.0000x reference)
//
#include <hip/hip_runtime.h>
#include <math.h>

#define EPSV 1e-5f
#define SCALE_W 0.0441941738241592f   /* 1/sqrt(512) */
#define GAIN_R 1.4142135623730951f    /* sqrt(2) */

typedef __attribute__((ext_vector_type(8))) short bf16x8;
typedef __attribute__((ext_vector_type(4))) float f32x4;

static __device__ __forceinline__ unsigned short f2bf(float f) {
  union { float f; unsigned int u; } v; v.f = f;
  unsigned int r = v.u + 0x7FFFu + ((v.u >> 16) & 1u);   // RNE
  return (unsigned short)(r >> 16);
}

#define GLD_LDS16(gsrc, ldst)                                                                      \
  __builtin_amdgcn_global_load_lds((const __attribute__((address_space(1))) unsigned int*)(gsrc),  \
                                   (__attribute__((address_space(3))) unsigned int*)(ldst), 16, 0, 0)

#define RED16(v) { v += __shfl_xor(v, 1); v += __shfl_xor(v, 2); v += __shfl_xor(v, 4); v += __shfl_xor(v, 8); }

// ---------------- pre-kernel: b = expmap0(bias), y2 = ||b||^2 ----------------
__global__ void bias_expmap_k(const float* __restrict__ bias, float* __restrict__ bexp,
                              float* __restrict__ y2out) {
  __shared__ float part[8];
  int t = threadIdx.x;
  float bv = bias[t];
  float s = bv * bv;
  s += __shfl_xor(s, 1);  s += __shfl_xor(s, 2);  s += __shfl_xor(s, 4);
  s += __shfl_xor(s, 8);  s += __shfl_xor(s, 16); s += __shfl_xor(s, 32);
  if ((t & 63) == 0) part[t >> 6] = s;
  __syncthreads();
  float tot = 0.f;
#pragma unroll
  for (int i = 0; i < 8; ++i) tot += part[i];
  float un = fmaxf(sqrtf(tot), EPSV);
  float th = tanhf(un);
  bexp[t] = th * bv / un;
  if (t == 0) *y2out = th * th;
}

// ---------------- pre-kernel: pack weight -> bf16, SCALE baked, padded K-step layout ----
// layout: ushort wsB[ks][col][40], data kk=0..31 at [col*40+kk], 8-ushort pad.
__global__ void pack_weight_k(const float* __restrict__ w, unsigned short* __restrict__ wsB) {
  int e = blockIdx.x * 256 + threadIdx.x;   // 0..262143
  int col = e >> 9;
  int k = e & 511;
  int ks = k >> 5;
  int kk = k & 31;
  wsB[ks * 20480 + col * 40 + kk] = f2bf(w[e] * SCALE_W);
}

// ---------------- main fused kernel ----------------
#define RB 80            /* LDS row bytes: 64 data + 16 pad */
#define BOFF 5120        /* B region offset = 64*80 */
#define SMEMSZ 46080     /* 5120 + 512*80 */

__global__ __launch_bounds__(512, 4)
void hyp_main_k(const float* __restrict__ x, const unsigned short* __restrict__ wsB,
                const float* __restrict__ bexp, const float* __restrict__ y2p,
                float* __restrict__ out) {
  extern __shared__ char smem[];
  const int tid  = threadIdx.x;
  const int lane = tid & 63;
  const int wave = tid >> 6;       // 0..7 : column group (64 cols each)
  const int l15  = lane & 15;
  const int lgr  = lane >> 4;      // 0..3
  const long brow = (long)blockIdx.x * 64;

  // A staging: thread t handles row t>>3, 4 floats at col (t&7)*4 (+32/step)
  const int arow  = tid >> 3;
  const int acol0 = (tid & 7) * 4;
  const float* xptr = x + (size_t)(brow + arow) * 512 + acol0;
  char* awr = smem + arow * RB + (tid & 7) * 8;

  const char* ard = smem + l15 * RB + lgr * 16;
  const char* brd = smem + BOFF + (wave * 64 + l15) * RB + lgr * 16;

  f32x4 acc[4][4];
#pragma unroll
  for (int i = 0; i < 4; ++i)
#pragma unroll
    for (int j = 0; j < 4; ++j) acc[i][j] = f32x4{0.f, 0.f, 0.f, 0.f};

  float xss = 0.f;

  for (int ks = 0; ks < 16; ++ks) {
    // stage A (fp32 -> bf16, accumulate row ||x||^2 partial for free)
    float4 xv = *(const float4*)(xptr + ks * 32);
    xss += xv.x * xv.x + xv.y * xv.y + xv.z * xv.z + xv.w * xv.w;
    unsigned int lo = (unsigned int)f2bf(xv.x) | ((unsigned int)f2bf(xv.y) << 16);
    unsigned int hi = (unsigned int)f2bf(xv.z) | ((unsigned int)f2bf(xv.w) << 16);
    uint2 pk; pk.x = lo; pk.y = hi;
    *(uint2*)awr = pk;
    // stage B: 40 KiB padded chunk via global_load_lds (5 x 1KiB per wave)
#pragma unroll
    for (int i = 0; i < 5; ++i) {
      const int chunk = wave * 5 + i;
      GLD_LDS16((const char*)wsB + (size_t)ks * 40960 + chunk * 1024 + lane * 16,
                smem + BOFF + chunk * 1024);
    }
    __syncthreads();
    bf16x8 af[4], bfr[4];
#pragma unroll
    for (int mf = 0; mf < 4; ++mf) af[mf] = *(const bf16x8*)(ard + mf * (16 * RB));
#pragma unroll
    for (int nf = 0; nf < 4; ++nf) bfr[nf] = *(const bf16x8*)(brd + nf * (16 * RB));
#pragma unroll
    for (int mf = 0; mf < 4; ++mf)
#pragma unroll
      for (int nf = 0; nf < 4; ++nf)
        acc[mf][nf] = __builtin_amdgcn_mfma_f32_16x16x32_bf16(af[mf], bfr[nf], acc[mf][nf], 0, 0, 0);
    __syncthreads();
  }

  // ---------------- fused hyperbolic epilogue ----------------
  float* xn2 = (float*)smem;            // [64]
  float* pS2 = (float*)(smem + 256);    // [64][8]
  float* pSB = (float*)(smem + 2304);   // [64][8]
  float* g12 = (float*)(smem + 4352);   // [64][2]
  float* pN2 = pS2;                     // reuse (safe: separated by barriers)
  float* tml = pSB;                     // reuse

  // row ||x||^2 : reduce 8 staging threads per row
  float xs = xss;
  xs += __shfl_xor(xs, 1); xs += __shfl_xor(xs, 2); xs += __shfl_xor(xs, 4);
  if ((lane & 7) == 0) xn2[wave * 8 + (lane >> 3)] = xs;

  float bv[4];
#pragma unroll
  for (int nf = 0; nf < 4; ++nf) bv[nf] = bexp[wave * 64 + nf * 16 + l15];

  // per-wave partials: S2 = sum mx^2, SB = sum mx*b over this wave's 64 cols
#pragma unroll
  for (int mf = 0; mf < 4; ++mf)
#pragma unroll
    for (int j = 0; j < 4; ++j) {
      float s2 = 0.f, sb = 0.f;
#pragma unroll
      for (int nf = 0; nf < 4; ++nf) {
        float v = acc[mf][nf][j];
        s2 += v * v;
        sb += v * bv[nf];
      }
      RED16(s2); RED16(sb);
      if (l15 == 0) {
        int r = mf * 16 + lgr * 4 + j;
        pS2[r * 8 + wave] = s2;
        pSB[r * 8 + wave] = sb;
      }
    }
  __syncthreads();

  // per-row scalars: mobius_matvec factor, mobius_add coeffs, project
  if (tid < 64) {
    int r = tid;
    float S2 = 0.f, SB = 0.f;
#pragma unroll
    for (int i = 0; i < 8; ++i) { S2 += pS2[r * 8 + i]; SB += pSB[r * 8 + i]; }
    float y2 = *y2p;
    float xn  = fmaxf(sqrtf(xn2[r]), EPSV);
    float mxn = fmaxf(sqrtf(S2), EPSV);
    float f = tanhf((mxn / xn) * atanhf(fminf(xn, 1.f - EPSV))) / mxn;  // mv = f*mx
    float xy = f * SB;
    float x2 = f * f * S2;
    float den = 1.f + 2.f * xy + x2 * y2 + EPSV;
    float g1 = (1.f + 2.f * xy + y2) * f / den;   // coeff on mx
    float g2 = (1.f - x2) / den;                  // coeff on b
    float n1sq = g1 * g1 * S2 + 2.f * g1 * g2 * SB + g2 * g2 * y2;
    float n1 = fmaxf(sqrtf(fmaxf(n1sq, 0.f)), EPSV);
    if (n1 > 0.999f) { float s = 0.999f / n1; g1 *= s; g2 *= s; }   // project()
    g12[r * 2] = g1; g12[r * 2 + 1] = g2;
  }
  __syncthreads();

  // pass 2: v = lrelu(g1*mx + g2*b); accumulate ||v||^2 ; keep v in acc
#pragma unroll
  for (int mf = 0; mf < 4; ++mf)
#pragma unroll
    for (int j = 0; j < 4; ++j) {
      int r = mf * 16 + lgr * 4 + j;
      float g1 = g12[r * 2], g2 = g12[r * 2 + 1];
      float s2 = 0.f;
#pragma unroll
      for (int nf = 0; nf < 4; ++nf) {
        float v = g1 * acc[mf][nf][j] + g2 * bv[nf];
        v = v > 0.f ? v : 0.2f * v;
        acc[mf][nf][j] = v;
        s2 += v * v;
      }
      RED16(s2);
      if (l15 == 0) pN2[r * 8 + wave] = s2;
    }
  __syncthreads();

  // mobius scalar mult factor
  if (tid < 64) {
    int r = tid;
    float s2 = 0.f;
#pragma unroll
    for (int i = 0; i < 8; ++i) s2 += pN2[r * 8 + i];
    float n2 = fmaxf(sqrtf(s2), EPSV);
    tml[r] = tanhf(GAIN_R * atanhf(fminf(n2, 1.f - EPSV))) / n2;
  }
  __syncthreads();

  // store
#pragma unroll
  for (int mf = 0; mf < 4; ++mf)
#pragma unroll
    for (int j = 0; j < 4; ++j) {
      int r = mf * 16 + lgr * 4 + j;
      float tm = tml[r];
#pragma unroll
      for (int nf = 0; nf < 4; ++nf)
        out[(size_t)(brow + r) * 512 + wave * 64 + nf * 16 + l15] = tm * acc[mf][nf][j];
    }
}

extern "C" void kernel_launch(void* const* d_in, const int* in_sizes, int n_in,
                              void* d_out, int out_size, void* d_ws, size_t ws_size,
                              hipStream_t stream) {
  const float* x    = (const float*)d_in[0];
  const float* w    = (const float*)d_in[1];
  const float* bias = (const float*)d_in[2];
  float* out = (float*)d_out;

  unsigned short* wsB = (unsigned short*)d_ws;                 // 655360 B
  float* bexp = (float*)((char*)d_ws + 655360);                // 2048 B
  float* y2p  = (float*)((char*)d_ws + 655360 + 2048);         // 4 B

  bias_expmap_k<<<dim3(1), dim3(512), 0, stream>>>(bias, bexp, y2p);
  pack_weight_k<<<dim3(1024), dim3(256), 0, stream>>>(w, wsB);

  const int nrows = in_sizes[0] / 512;      // 131072
  hyp_main_k<<<dim3(nrows / 64), dim3(512), SMEMSZ, stream>>>(x, wsB, bexp, y2p, out);
}

// Round 2
// 213.603 us; speedup vs baseline: 1.2847x; 1.2847x over previous
//
#include <hip/hip_runtime.h>
#include <math.h>

#define EPSV 1e-5f
#define SCALE_W 0.0441941738241592f   /* 1/sqrt(512) */
#define GAIN_R 1.4142135623730951f    /* sqrt(2) */

typedef __attribute__((ext_vector_type(8))) short bf16x8;
typedef __attribute__((ext_vector_type(4))) float f32x4;

static __device__ __forceinline__ unsigned short f2bf(float f) {
  union { float f; unsigned int u; } v; v.f = f;
  unsigned int r = v.u + 0x7FFFu + ((v.u >> 16) & 1u);   // RNE
  return (unsigned short)(r >> 16);
}

#define RED16(v) { v += __shfl_xor(v, 1); v += __shfl_xor(v, 2); v += __shfl_xor(v, 4); v += __shfl_xor(v, 8); }

// ---------------- pre-kernel: b = expmap0(bias), y2 = ||b||^2 ----------------
__global__ void bias_expmap_k(const float* __restrict__ bias, float* __restrict__ bexp,
                              float* __restrict__ y2out) {
  __shared__ float part[8];
  int t = threadIdx.x;
  float bv = bias[t];
  float s = bv * bv;
  s += __shfl_xor(s, 1);  s += __shfl_xor(s, 2);  s += __shfl_xor(s, 4);
  s += __shfl_xor(s, 8);  s += __shfl_xor(s, 16); s += __shfl_xor(s, 32);
  if ((t & 63) == 0) part[t >> 6] = s;
  __syncthreads();
  float tot = 0.f;
#pragma unroll
  for (int i = 0; i < 8; ++i) tot += part[i];
  float un = fmaxf(sqrtf(tot), EPSV);
  float th = tanhf(un);
  bexp[t] = th * bv / un;
  if (t == 0) *y2out = th * th;
}

// ---------------- pre-kernel: pack weight -> bf16 B-fragments, SCALE baked ----
// dst chunk index = (ks*32 + colhi)*64 + lgr*16 + l15, 8 ushorts (j) per chunk.
// Lane l of a wave loading chunk base+(l) gets B[col=colhi*16+(l&15)][k=ks*32+(l>>4)*8+j].
__global__ void pack_weight_k(const float* __restrict__ w, unsigned short* __restrict__ wsB) {
  int e = blockIdx.x * 256 + threadIdx.x;   // 0..262143
  int o = e >> 9;          // output col (row of W)
  int k = e & 511;
  int ks = k >> 5, kk = k & 31;
  int lgr = kk >> 3, j = kk & 7;
  int colhi = o >> 4, l15 = o & 15;
  int dst = ((ks * 32 + colhi) * 64 + lgr * 16 + l15) * 8 + j;
  wsB[dst] = f2bf(w[e] * SCALE_W);
}

// ---------------- main fused kernel ----------------
// LDS: A tile [ks=16][row=64][80B] = 81920 B (32 data ushorts + 8 pad per row).
// Epilogue reuses: tds (transpose) at [0,33024), scalars at +40960.
#define RB 80
#define KSB 5120         /* 64*80 */
#define SMEMSZ 81920

__global__ __launch_bounds__(512, 4)
void hyp_main_k(const float* __restrict__ x, const unsigned short* __restrict__ wsB,
                const float* __restrict__ bexp, const float* __restrict__ y2p,
                float* __restrict__ out) {
  extern __shared__ char smem[];
  const int tid  = threadIdx.x;
  const int lane = tid & 63;
  const int wave = tid >> 6;       // 0..7 : column group (64 cols each)
  const int l15  = lane & 15;
  const int lgr  = lane >> 4;      // 0..3
  const long brow = (long)blockIdx.x * 64;

  // ---- A staging: thread t handles row t>>3, 4 floats at col (t&7)*4 + 32*ks ----
  const int arow  = tid >> 3;
  const float* xptr = x + (size_t)(brow + arow) * 512 + (tid & 7) * 4;
  char* awr = smem + arow * RB + (tid & 7) * 8;

  float xss = 0.f;
  {
    float4 buf[8];
#pragma unroll
    for (int i = 0; i < 8; ++i) buf[i] = *(const float4*)(xptr + i * 32);
#pragma unroll
    for (int ks = 0; ks < 16; ++ks) {
      float4 v = buf[ks & 7];
      if (ks < 8) buf[ks & 7] = *(const float4*)(xptr + (ks + 8) * 32);
      xss += v.x * v.x + v.y * v.y + v.z * v.z + v.w * v.w;
      uint2 pk;
      pk.x = (unsigned int)f2bf(v.x) | ((unsigned int)f2bf(v.y) << 16);
      pk.y = (unsigned int)f2bf(v.z) | ((unsigned int)f2bf(v.w) << 16);
      *(uint2*)(awr + ks * KSB) = pk;
    }
  }
  __syncthreads();   // A resident for all 16 K-steps; the ONLY pre-epilogue barrier

  // ---- barrier-free K-loop: LDS A frags + L2-resident global B frags ----
  const char* ard = smem + l15 * RB + lgr * 16;                    // + mf*1280 + ks*5120
  const char* brd = (const char*)wsB + ((size_t)(wave * 4) * 64 + lane) * 16;  // + nf*1024 + ks*32768

  f32x4 acc[4][4];
#pragma unroll
  for (int i = 0; i < 4; ++i)
#pragma unroll
    for (int j = 0; j < 4; ++j) acc[i][j] = f32x4{0.f, 0.f, 0.f, 0.f};

#pragma unroll 4
  for (int ks = 0; ks < 16; ++ks) {
    bf16x8 af[4], bfr[4];
#pragma unroll
    for (int mf = 0; mf < 4; ++mf) af[mf] = *(const bf16x8*)(ard + ks * KSB + mf * (16 * RB));
#pragma unroll
    for (int nf = 0; nf < 4; ++nf) bfr[nf] = *(const bf16x8*)(brd + (size_t)ks * 32768 + nf * 1024);
#pragma unroll
    for (int mf = 0; mf < 4; ++mf)
#pragma unroll
      for (int nf = 0; nf < 4; ++nf)
        acc[mf][nf] = __builtin_amdgcn_mfma_f32_16x16x32_bf16(af[mf], bfr[nf], acc[mf][nf], 0, 0, 0);
  }
  __syncthreads();   // A region dead; epilogue may reuse LDS

  // ---------------- fused hyperbolic epilogue ----------------
  float* tds = (float*)smem;                       // [16][516] transpose staging
  float* xn2 = (float*)(smem + 40960);             // [64]
  float* pS2 = (float*)(smem + 40960 + 256);       // [64][8]
  float* pSB = (float*)(smem + 40960 + 2304);      // [64][8]
  float* g12 = (float*)(smem + 40960 + 4352);      // [64][2]
  float* pN2 = pS2;                                // reuse (barrier-separated)
  float* tml = pSB;                                // reuse

  // row ||x||^2 : reduce 8 staging threads per row
  float xs = xss;
  xs += __shfl_xor(xs, 1); xs += __shfl_xor(xs, 2); xs += __shfl_xor(xs, 4);
  if ((lane & 7) == 0) xn2[wave * 8 + (lane >> 3)] = xs;

  float bv[4];
#pragma unroll
  for (int nf = 0; nf < 4; ++nf) bv[nf] = bexp[wave * 64 + nf * 16 + l15];

  // per-wave partials: S2 = sum mx^2, SB = sum mx*b over this wave's 64 cols
#pragma unroll
  for (int mf = 0; mf < 4; ++mf)
#pragma unroll
    for (int j = 0; j < 4; ++j) {
      float s2 = 0.f, sb = 0.f;
#pragma unroll
      for (int nf = 0; nf < 4; ++nf) {
        float v = acc[mf][nf][j];
        s2 += v * v;
        sb += v * bv[nf];
      }
      RED16(s2); RED16(sb);
      if (l15 == 0) {
        int r = mf * 16 + lgr * 4 + j;
        pS2[r * 8 + wave] = s2;
        pSB[r * 8 + wave] = sb;
      }
    }
  __syncthreads();

  // per-row scalars: mobius_matvec factor, mobius_add coeffs, project
  if (tid < 64) {
    int r = tid;
    float S2 = 0.f, SB = 0.f;
#pragma unroll
    for (int i = 0; i < 8; ++i) { S2 += pS2[r * 8 + i]; SB += pSB[r * 8 + i]; }
    float y2 = *y2p;
    float xn  = fmaxf(sqrtf(xn2[r]), EPSV);
    float mxn = fmaxf(sqrtf(S2), EPSV);
    float f = tanhf((mxn / xn) * atanhf(fminf(xn, 1.f - EPSV))) / mxn;  // mv = f*mx
    float xy = f * SB;
    float x2 = f * f * S2;
    float den = 1.f + 2.f * xy + x2 * y2 + EPSV;
    float g1 = (1.f + 2.f * xy + y2) * f / den;   // coeff on mx
    float g2 = (1.f - x2) / den;                  // coeff on b
    float n1sq = g1 * g1 * S2 + 2.f * g1 * g2 * SB + g2 * g2 * y2;
    float n1 = fmaxf(sqrtf(fmaxf(n1sq, 0.f)), EPSV);
    if (n1 > 0.999f) { float s = 0.999f / n1; g1 *= s; g2 *= s; }   // project()
    g12[r * 2] = g1; g12[r * 2 + 1] = g2;
  }
  __syncthreads();

  // pass 2: v = lrelu(g1*mx + g2*b); accumulate ||v||^2 ; keep v in acc
#pragma unroll
  for (int mf = 0; mf < 4; ++mf)
#pragma unroll
    for (int j = 0; j < 4; ++j) {
      int r = mf * 16 + lgr * 4 + j;
      float g1 = g12[r * 2], g2 = g12[r * 2 + 1];
      float s2 = 0.f;
#pragma unroll
      for (int nf = 0; nf < 4; ++nf) {
        float v = g1 * acc[mf][nf][j] + g2 * bv[nf];
        v = v > 0.f ? v : 0.2f * v;
        acc[mf][nf][j] = v;
        s2 += v * v;
      }
      RED16(s2);
      if (l15 == 0) pN2[r * 8 + wave] = s2;
    }
  __syncthreads();

  // mobius scalar mult factor
  if (tid < 64) {
    int r = tid;
    float s2 = 0.f;
#pragma unroll
    for (int i = 0; i < 8; ++i) s2 += pN2[r * 8 + i];
    float n2 = fmaxf(sqrtf(s2), EPSV);
    tml[r] = tanhf(GAIN_R * atanhf(fminf(n2, 1.f - EPSV))) / n2;
  }
  __syncthreads();

  // ---- store: transpose through LDS so each wave writes 1KB contiguous lines ----
#pragma unroll
  for (int mf = 0; mf < 4; ++mf) {
    __syncthreads();   // previous read-phase (or tml calc) done before overwrite
#pragma unroll
    for (int j = 0; j < 4; ++j) {
      int rl = lgr * 4 + j;
      float tm = tml[mf * 16 + rl];
#pragma unroll
      for (int nf = 0; nf < 4; ++nf)
        tds[rl * 516 + wave * 64 + nf * 16 + l15] = tm * acc[mf][nf][j];
    }
    __syncthreads();
#pragma unroll
    for (int i = 0; i < 4; ++i) {
      int fi = i * 512 + tid;
      int row = fi >> 7, c4 = fi & 127;
      float4 v = *(const float4*)(tds + row * 516 + c4 * 4);
      *(float4*)(out + (size_t)(brow + mf * 16 + row) * 512 + c4 * 4) = v;
    }
  }
}

extern "C" void kernel_launch(void* const* d_in, const int* in_sizes, int n_in,
                              void* d_out, int out_size, void* d_ws, size_t ws_size,
                              hipStream_t stream) {
  const float* x    = (const float*)d_in[0];
  const float* w    = (const float*)d_in[1];
  const float* bias = (const float*)d_in[2];
  float* out = (float*)d_out;

  unsigned short* wsB = (unsigned short*)d_ws;                 // 524288 B
  float* bexp = (float*)((char*)d_ws + 524288);                // 2048 B
  float* y2p  = (float*)((char*)d_ws + 524288 + 2048);         // 4 B

  bias_expmap_k<<<dim3(1), dim3(512), 0, stream>>>(bias, bexp, y2p);
  pack_weight_k<<<dim3(1024), dim3(256), 0, stream>>>(w, wsB);

  const int nrows = in_sizes[0] / 512;      // 131072
  hyp_main_k<<<dim3(nrows / 64), dim3(512), SMEMSZ, stream>>>(x, wsB, bexp, y2p, out);
}